// Round 6
// baseline (917.895 us; speedup 1.0000x reference)
//
#include <hip/hip_runtime.h>

#define NN   100000
#define TL   128
#define OC   5
#define KW   7
#define ST   3
#define CL   41          // (128-7)/3+1
#define FLAT 205         // 5*41
#define EMB  32
#define HID  16
#define NE   3200000

#define BSH    7                       // 128 dst-nodes per bucket
#define BNODES 128
#define NBKT   ((NN + BNODES - 1) / BNODES)   // 782 dst buckets
#define NHALF  50000                   // src split point
#define NBKT2  (NBKT * 2)              // (src_half, dst_bucket) buckets
#define FILL_CHUNK 16384
#define SPLIT  2                       // blocks per (bucket,half) in k_bagg

// ===========================================================================
// Embedding path: conv -> Ht (j-major), fused fc+g1w1 -> p1
// ===========================================================================
__global__ __launch_bounds__(256) void k_prep(
    const float* __restrict__ g1w1, const float* __restrict__ fc_w,
    const float* __restrict__ fc_b,
    float* __restrict__ wcT, float* __restrict__ bc)
{
    int tid = threadIdx.x;
    for (int idx = tid; idx < FLAT * HID; idx += 256) {
        int l = idx & 15;
        int j = idx >> 4;
        float s = 0.f;
        #pragma unroll
        for (int m = 0; m < EMB; ++m)
            s = fmaf(g1w1[l * EMB + m], fc_w[m * FLAT + j], s);
        wcT[j * HID + l] = s;
    }
    if (tid < HID) {
        float s = 0.f;
        #pragma unroll
        for (int m = 0; m < EMB; ++m)
            s = fmaf(g1w1[tid * EMB + m], fc_b[m], s);
        bc[tid] = s;
    }
}

__global__ __launch_bounds__(256) void k_conv(
    const float* __restrict__ x,
    const float* __restrict__ conv_w, const float* __restrict__ conv_b,
    float* __restrict__ Ht)
{
    __shared__ float s_x[64 * 129];
    const int tid = threadIdx.x;
    const long long n0 = (long long)blockIdx.x * 64;
    const int nvalid = min(64, NN - (int)n0);

    const float4* xv = (const float4*)(x + n0 * TL);
    #pragma unroll
    for (int c = 0; c < 8; ++c) {
        int f4  = c * 256 + tid;
        int row = f4 >> 5;
        int c4  = f4 & 31;
        if (row < nvalid) {
            float4 v = xv[f4];
            float* d = s_x + row * 129 + c4 * 4;
            d[0] = v.x; d[1] = v.y; d[2] = v.z; d[3] = v.w;
        }
    }
    __syncthreads();

    for (int idx = tid; idx < FLAT * 64; idx += 256) {
        int n = idx & 63;
        int o = idx >> 6;
        int c = o / CL;
        int t = o - c * CL;
        float acc = conv_b[c];
        const float* wr = conv_w + c * KW;
        const float* xr = s_x + n * 129 + t * ST;
        #pragma unroll
        for (int k = 0; k < KW; ++k)
            acc = fmaf(xr[k], wr[k], acc);
        if (n < nvalid)
            Ht[(size_t)o * NN + n0 + n] = fmaxf(acc, 0.f);
    }
}

__global__ __launch_bounds__(256) void k_fc(
    const float* __restrict__ Ht, const float* __restrict__ wcT,
    const float* __restrict__ bc, float* __restrict__ p1)
{
    int n = blockIdx.x * 256 + threadIdx.x;
    if (n >= NN) return;

    float acc[HID];
    #pragma unroll
    for (int l = 0; l < HID; ++l) acc[l] = bc[l];

    #pragma unroll 5
    for (int j = 0; j < FLAT; ++j) {
        float h = Ht[(size_t)j * NN + n];
        const float* w = wcT + j * HID;
        #pragma unroll
        for (int l = 0; l < HID; ++l)
            acc[l] = fmaf(h, w[l], acc[l]);
    }

    float4* po = (float4*)(p1 + (size_t)n * HID);
    po[0] = make_float4(acc[0],  acc[1],  acc[2],  acc[3]);
    po[1] = make_float4(acc[4],  acc[5],  acc[6],  acc[7]);
    po[2] = make_float4(acc[8],  acc[9],  acc[10], acc[11]);
    po[3] = make_float4(acc[12], acc[13], acc[14], acc[15]);
}

// ===========================================================================
// 2-D edge binning: bucket = src_half * NBKT + (dst >> 7).
// Launch-time split by src_half makes each k_bagg launch's gather table a
// 3.2-MB slice of p -> resident in every XCD's 4-MB L2.
// ===========================================================================
__global__ __launch_bounds__(256) void k_bhist(
    const int* __restrict__ ei, int* __restrict__ bcnt)
{
    __shared__ int h[NBKT2];
    for (int i = threadIdx.x; i < NBKT2; i += 256) h[i] = 0;
    __syncthreads();
    for (long long e = (long long)blockIdx.x * 256 + threadIdx.x; e < NE;
         e += (long long)gridDim.x * 256) {
        int src = ei[e];
        int dst = ei[NE + e];
        int b = (src >= NHALF ? NBKT : 0) + (dst >> BSH);
        atomicAdd(&h[b], 1);
    }
    __syncthreads();
    for (int i = threadIdx.x; i < NBKT2; i += 256)
        if (h[i]) atomicAdd(&bcnt[i], h[i]);
}

__global__ __launch_bounds__(256) void k_bscan(
    const int* __restrict__ bcnt, int* __restrict__ bbase)
{
    __shared__ int s[256];
    const int tid = threadIdx.x;
    const int chunk = (NBKT2 + 255) / 256;   // 7
    int lo = tid * chunk;
    int hi = min(lo + chunk, NBKT2);
    int sum = 0;
    for (int i = lo; i < hi; ++i) sum += bcnt[i];
    s[tid] = sum;
    __syncthreads();
    if (tid == 0) {
        int run = 0;
        for (int i = 0; i < 256; ++i) { int v = s[i]; s[i] = run; run += v; }
        bbase[NBKT2] = NE;
    }
    __syncthreads();
    int run = s[tid];
    for (int i = lo; i < hi; ++i) { bbase[i] = run; run += bcnt[i]; }
}

// Block-grouped fill: per-block LDS histogram -> one range-reservation atomic
// per (block,bucket) -> contiguous packed writes.  packed = dst_local<<20|src.
__global__ __launch_bounds__(256) void k_bfill(
    const int* __restrict__ ei, int* __restrict__ bcur,
    unsigned* __restrict__ packed)
{
    __shared__ int h[NBKT2];
    const long long e0 = (long long)blockIdx.x * FILL_CHUNK;
    const int cnt = (int)min((long long)FILL_CHUNK, (long long)NE - e0);

    for (int i = threadIdx.x; i < NBKT2; i += 256) h[i] = 0;
    __syncthreads();
    for (int i = threadIdx.x; i < cnt; i += 256) {
        int src = ei[e0 + i];
        int dst = ei[NE + e0 + i];
        atomicAdd(&h[(src >= NHALF ? NBKT : 0) + (dst >> BSH)], 1);
    }
    __syncthreads();
    for (int i = threadIdx.x; i < NBKT2; i += 256) {
        int c = h[i];
        h[i] = c ? atomicAdd(&bcur[i], c) : 0;   // h[i] becomes write cursor
    }
    __syncthreads();
    for (int i = threadIdx.x; i < cnt; i += 256) {
        int src = ei[e0 + i];
        int dst = ei[NE + e0 + i];
        int b = (src >= NHALF ? NBKT : 0) + (dst >> BSH);
        int slot = atomicAdd(&h[b], 1);
        packed[slot] = ((unsigned)(dst & (BNODES - 1)) << 20) | (unsigned)src;
    }
}

// ===========================================================================
// Bucketed aggregation over ONE src-half (bofs selects half): SPLIT blocks
// per dst-bucket, private LDS tile, x4-unrolled gathers (L2-resident table),
// coalesced global-atomic flush.  agg must be pre-zeroed.
// ===========================================================================
__global__ __launch_bounds__(256) void k_bagg(
    const float* __restrict__ p, const int* __restrict__ bbase,
    const unsigned* __restrict__ packed, float* __restrict__ agg, int bofs)
{
    __shared__ float tile[BNODES * HID];   // 8 KB
    const int bl = blockIdx.x >> 1;        // dst bucket (SPLIT==2)
    const int s  = blockIdx.x & 1;         // split index
    const int n0 = bl << BSH;
    const int nv = min(BNODES, NN - n0);

    for (int i = threadIdx.x; i < BNODES * HID; i += 256) tile[i] = 0.f;
    __syncthreads();

    const int L = bbase[bofs + bl], H = bbase[bofs + bl + 1];
    const int len = H - L;
    const int lo = L + ((len * s) >> 1);
    const int hi = L + ((len * (s + 1)) >> 1);

    const int k = threadIdx.x & 15;
    const int g = threadIdx.x >> 4;        // 16 edge-groups per block
    int i = lo + g;
    for (; i + 48 < hi; i += 64) {
        unsigned pk0 = packed[i];
        unsigned pk1 = packed[i + 16];
        unsigned pk2 = packed[i + 32];
        unsigned pk3 = packed[i + 48];
        float v0 = p[(size_t)(pk0 & 0xFFFFFu) * HID + k];
        float v1 = p[(size_t)(pk1 & 0xFFFFFu) * HID + k];
        float v2 = p[(size_t)(pk2 & 0xFFFFFu) * HID + k];
        float v3 = p[(size_t)(pk3 & 0xFFFFFu) * HID + k];
        atomicAdd(&tile[(pk0 >> 20) * HID + k], v0);
        atomicAdd(&tile[(pk1 >> 20) * HID + k], v1);
        atomicAdd(&tile[(pk2 >> 20) * HID + k], v2);
        atomicAdd(&tile[(pk3 >> 20) * HID + k], v3);
    }
    for (; i < hi; i += 16) {
        unsigned pk = packed[i];
        float v = p[(size_t)(pk & 0xFFFFFu) * HID + k];
        atomicAdd(&tile[(pk >> 20) * HID + k], v);
    }
    __syncthreads();

    for (int j = threadIdx.x; j < nv * HID; j += 256)
        atomicAdd(&agg[(size_t)n0 * HID + j], tile[j]);
}

// ===========================================================================
// MLP epilogues (unchanged)
// ===========================================================================
__global__ __launch_bounds__(256) void k_mlp1(
    const float* __restrict__ p1, const float* __restrict__ agg,
    const float* __restrict__ b1, const float* __restrict__ w2,
    const float* __restrict__ b2, const float* __restrict__ w3,
    float* __restrict__ p2)
{
    __shared__ float s_w2[HID * HID], s_w3[HID * HID], s_b1[HID], s_b2[HID];
    int tid = threadIdx.x;
    s_w2[tid] = w2[tid];
    s_w3[tid] = w3[tid];
    if (tid < HID) { s_b1[tid] = b1[tid]; s_b2[tid] = b2[tid]; }
    __syncthreads();

    int n = blockIdx.x * 256 + tid;
    if (n >= NN) return;

    float t[HID], h[HID];
    const float4* pa = (const float4*)(p1  + (size_t)n * HID);
    const float4* pb = (const float4*)(agg + (size_t)n * HID);
    #pragma unroll
    for (int i = 0; i < 4; ++i) {
        float4 a = pa[i], b = pb[i];
        t[i*4+0] = fmaxf(a.x + b.x + s_b1[i*4+0], 0.f);
        t[i*4+1] = fmaxf(a.y + b.y + s_b1[i*4+1], 0.f);
        t[i*4+2] = fmaxf(a.z + b.z + s_b1[i*4+2], 0.f);
        t[i*4+3] = fmaxf(a.w + b.w + s_b1[i*4+3], 0.f);
    }
    #pragma unroll
    for (int i = 0; i < HID; ++i) {
        float acc = s_b2[i];
        #pragma unroll
        for (int j = 0; j < HID; ++j) acc += t[j] * s_w2[i * HID + j];
        h[i] = fmaxf(acc, 0.f);
    }
    float o[HID];
    #pragma unroll
    for (int i = 0; i < HID; ++i) {
        float acc = 0.f;
        #pragma unroll
        for (int j = 0; j < HID; ++j) acc += h[j] * s_w3[i * HID + j];
        o[i] = acc;
    }
    float4* po = (float4*)(p2 + (size_t)n * HID);
    #pragma unroll
    for (int i = 0; i < 4; ++i)
        po[i] = make_float4(o[i*4+0], o[i*4+1], o[i*4+2], o[i*4+3]);
}

__global__ __launch_bounds__(256) void k_final(
    const float* __restrict__ p2, const float* __restrict__ agg2,
    const float* __restrict__ b1, const float* __restrict__ w2,
    const float* __restrict__ b2, const float* __restrict__ row,
    const float* __restrict__ rob,
    float* __restrict__ out)
{
    __shared__ float s_w2[HID * HID], s_b1[HID], s_b2[HID], s_ro[HID];
    int tid = threadIdx.x;
    s_w2[tid] = w2[tid];
    if (tid < HID) { s_b1[tid] = b1[tid]; s_b2[tid] = b2[tid]; s_ro[tid] = row[tid]; }
    __syncthreads();

    int n = blockIdx.x * 256 + tid;
    if (n >= NN) return;

    float t[HID];
    const float4* pa = (const float4*)(p2   + (size_t)n * HID);
    const float4* pb = (const float4*)(agg2 + (size_t)n * HID);
    #pragma unroll
    for (int i = 0; i < 4; ++i) {
        float4 a = pa[i], b = pb[i];
        t[i*4+0] = fmaxf(a.x + b.x + s_b1[i*4+0], 0.f);
        t[i*4+1] = fmaxf(a.y + b.y + s_b1[i*4+1], 0.f);
        t[i*4+2] = fmaxf(a.z + b.z + s_b1[i*4+2], 0.f);
        t[i*4+3] = fmaxf(a.w + b.w + s_b1[i*4+3], 0.f);
    }
    float res = rob[0];
    #pragma unroll
    for (int i = 0; i < HID; ++i) {
        float acc = s_b2[i];
        #pragma unroll
        for (int j = 0; j < HID; ++j) acc += t[j] * s_w2[i * HID + j];
        res += acc * s_ro[i];
    }
    out[n] = res;
}

// ===========================================================================
// Fallback (round-1 structure) — only if workspace too small
// ===========================================================================
__global__ __launch_bounds__(256) void k_embed(
    const float* __restrict__ x,
    const float* __restrict__ conv_w, const float* __restrict__ conv_b,
    const float* __restrict__ fc_w,   const float* __restrict__ fc_b,
    const float* __restrict__ g1w1,
    float* __restrict__ p1)
{
    __shared__ float s_x[4][TL];
    __shared__ float s_h[4][FLAT + 3];
    __shared__ float s_e[4][EMB];

    const int w    = threadIdx.x >> 6;
    const int lane = threadIdx.x & 63;
    const int node = blockIdx.x * 4 + w;

    const float2* xr = (const float2*)(x + (size_t)node * TL);
    float2 v = xr[lane];
    s_x[w][lane * 2 + 0] = v.x;
    s_x[w][lane * 2 + 1] = v.y;
    __syncthreads();

    for (int o = lane; o < FLAT; o += 64) {
        int c = o / CL;
        int t = o - c * CL;
        float acc = conv_b[c];
        #pragma unroll
        for (int k = 0; k < KW; ++k)
            acc += s_x[w][t * ST + k] * conv_w[c * KW + k];
        s_h[w][o] = fmaxf(acc, 0.f);
    }
    __syncthreads();

    if (lane < EMB) {
        float acc = fc_b[lane];
        const float* wr = fc_w + lane * FLAT;
        for (int j = 0; j < FLAT; ++j)
            acc += s_h[w][j] * wr[j];
        s_e[w][lane] = acc;
    }
    __syncthreads();

    if (lane < HID) {
        float acc = 0.f;
        const float* wr = g1w1 + lane * EMB;
        #pragma unroll
        for (int j = 0; j < EMB; ++j)
            acc += s_e[w][j] * wr[j];
        p1[(size_t)node * HID + lane] = acc;
    }
}

__global__ __launch_bounds__(256) void k_scatter(
    const float* __restrict__ p, const int* __restrict__ ei,
    float* __restrict__ agg)
{
    long long t = (long long)blockIdx.x * 256 + threadIdx.x;
    int e = (int)(t >> 4);
    int k = (int)(t & 15);
    if (e >= NE) return;
    int src = ei[e];
    int dst = ei[NE + e];
    float v = p[(size_t)src * HID + k];
    atomicAdd(agg + (size_t)dst * HID + k, v);
}

// ===========================================================================
extern "C" void kernel_launch(void* const* d_in, const int* in_sizes, int n_in,
                              void* d_out, int out_size, void* d_ws, size_t ws_size,
                              hipStream_t stream)
{
    const float* x      = (const float*)d_in[0];
    const int*   ei     = (const int*)  d_in[1];
    const float* conv_w = (const float*)d_in[2];
    const float* conv_b = (const float*)d_in[3];
    const float* fc_w   = (const float*)d_in[4];
    const float* fc_b   = (const float*)d_in[5];
    const float* g1w1   = (const float*)d_in[6];
    const float* g1b1   = (const float*)d_in[7];
    const float* g1w2   = (const float*)d_in[8];
    const float* g1b2   = (const float*)d_in[9];
    const float* g2w1   = (const float*)d_in[10];
    const float* g2b1   = (const float*)d_in[11];
    const float* g2w2   = (const float*)d_in[12];
    const float* g2b2   = (const float*)d_in[13];
    const float* ro_w   = (const float*)d_in[14];
    const float* ro_b   = (const float*)d_in[15];
    float* out = (float*)d_out;

    // workspace: A[NN*16] B[NN*16] wcT[205*16] bc[16] Ht[205*NN]
    // Ht region reused after k_fc for: bcnt[NBKT2] bbase[NBKT2+1] bcur[NBKT2]
    //                                  packed[NE]  (~12.8 MB << 82 MB)
    float* A   = (float*)d_ws;
    float* B   = A + (size_t)NN * HID;
    float* wcT = B + (size_t)NN * HID;
    float* bc  = wcT + (size_t)FLAT * HID;
    float* Ht  = bc + 16;
    const size_t need = ((size_t)NN * HID * 2 + (size_t)FLAT * HID + 16 +
                         (size_t)FLAT * NN) * sizeof(float);

    int* bcnt  = (int*)Ht;
    int* bbase = bcnt + NBKT2;
    int* bcur  = bbase + NBKT2 + 1;
    unsigned* packed = (unsigned*)(bcur + NBKT2);

    if (ws_size >= need) {
        // embedding
        k_prep<<<1, 256, 0, stream>>>(g1w1, fc_w, fc_b, wcT, bc);
        k_conv<<<(NN + 63) / 64, 256, 0, stream>>>(x, conv_w, conv_b, Ht);
        k_fc<<<(NN + 255) / 256, 256, 0, stream>>>(Ht, wcT, bc, A);

        // 2-D bucket binning (Ht region dead now)
        hipMemsetAsync(bcnt, 0, NBKT2 * sizeof(int), stream);
        k_bhist<<<1024, 256, 0, stream>>>(ei, bcnt);
        k_bscan<<<1, 256, 0, stream>>>(bcnt, bbase);
        hipMemcpyAsync(bcur, bbase, NBKT2 * sizeof(int),
                       hipMemcpyDeviceToDevice, stream);
        k_bfill<<<(NE + FILL_CHUNK - 1) / FILL_CHUNK, 256, 0, stream>>>(
            ei, bcur, packed);

        // GIN layer 1: two src-half passes, each with L2-resident table slice
        hipMemsetAsync(B, 0, (size_t)NN * HID * sizeof(float), stream);
        k_bagg<<<NBKT * SPLIT, 256, 0, stream>>>(A, bbase, packed, B, 0);
        k_bagg<<<NBKT * SPLIT, 256, 0, stream>>>(A, bbase, packed, B, NBKT);
        k_mlp1<<<(NN + 255) / 256, 256, 0, stream>>>(A, B, g1b1, g1w2, g1b2,
                                                     g2w1, A);
        // GIN layer 2
        hipMemsetAsync(B, 0, (size_t)NN * HID * sizeof(float), stream);
        k_bagg<<<NBKT * SPLIT, 256, 0, stream>>>(A, bbase, packed, B, 0);
        k_bagg<<<NBKT * SPLIT, 256, 0, stream>>>(A, bbase, packed, B, NBKT);
        k_final<<<(NN + 255) / 256, 256, 0, stream>>>(A, B, g2b1, g2w2, g2b2,
                                                      ro_w, ro_b, out);
    } else {
        // fallback: round-1 structure
        k_embed<<<NN / 4, 256, 0, stream>>>(x, conv_w, conv_b, fc_w, fc_b,
                                            g1w1, A);
        hipMemsetAsync(B, 0, (size_t)NN * HID * sizeof(float), stream);
        k_scatter<<<(int)(((long long)NE * HID) / 256), 256, 0, stream>>>(A, ei, B);
        k_mlp1<<<(NN + 255) / 256, 256, 0, stream>>>(A, B, g1b1, g1w2, g1b2,
                                                     g2w1, A);
        hipMemsetAsync(B, 0, (size_t)NN * HID * sizeof(float), stream);
        k_scatter<<<(int)(((long long)NE * HID) / 256), 256, 0, stream>>>(A, ei, B);
        k_final<<<(NN + 255) / 256, 256, 0, stream>>>(A, B, g2b1, g2w2, g2b2,
                                                      ro_w, ro_b, out);
    }
}

// Round 7
// 694.995 us; speedup vs baseline: 1.3207x; 1.3207x over previous
//
#include <hip/hip_runtime.h>

#define NN   100000
#define TL   128
#define OC   5
#define KW   7
#define ST   3
#define CL   41          // (128-7)/3+1
#define FLAT 205         // 5*41
#define EMB  32
#define HID  16
#define NE   3200000

#define BSH    7                       // 128 dst-nodes per bucket
#define BNODES 128
#define NBKT   ((NN + BNODES - 1) / BNODES)   // 782 dst buckets
#define FILL_CHUNK 16384

// ===========================================================================
// Embedding path: conv -> Ht (j-major), fused fc+g1w1 -> p1
// ===========================================================================
__global__ __launch_bounds__(256) void k_prep(
    const float* __restrict__ g1w1, const float* __restrict__ fc_w,
    const float* __restrict__ fc_b,
    float* __restrict__ wcT, float* __restrict__ bc)
{
    int tid = threadIdx.x;
    for (int idx = tid; idx < FLAT * HID; idx += 256) {
        int l = idx & 15;
        int j = idx >> 4;
        float s = 0.f;
        #pragma unroll
        for (int m = 0; m < EMB; ++m)
            s = fmaf(g1w1[l * EMB + m], fc_w[m * FLAT + j], s);
        wcT[j * HID + l] = s;
    }
    if (tid < HID) {
        float s = 0.f;
        #pragma unroll
        for (int m = 0; m < EMB; ++m)
            s = fmaf(g1w1[tid * EMB + m], fc_b[m], s);
        bc[tid] = s;
    }
}

__global__ __launch_bounds__(256) void k_conv(
    const float* __restrict__ x,
    const float* __restrict__ conv_w, const float* __restrict__ conv_b,
    float* __restrict__ Ht)
{
    __shared__ float s_x[64 * 129];
    const int tid = threadIdx.x;
    const long long n0 = (long long)blockIdx.x * 64;
    const int nvalid = min(64, NN - (int)n0);

    const float4* xv = (const float4*)(x + n0 * TL);
    #pragma unroll
    for (int c = 0; c < 8; ++c) {
        int f4  = c * 256 + tid;
        int row = f4 >> 5;
        int c4  = f4 & 31;
        if (row < nvalid) {
            float4 v = xv[f4];
            float* d = s_x + row * 129 + c4 * 4;
            d[0] = v.x; d[1] = v.y; d[2] = v.z; d[3] = v.w;
        }
    }
    __syncthreads();

    for (int idx = tid; idx < FLAT * 64; idx += 256) {
        int n = idx & 63;
        int o = idx >> 6;
        int c = o / CL;
        int t = o - c * CL;
        float acc = conv_b[c];
        const float* wr = conv_w + c * KW;
        const float* xr = s_x + n * 129 + t * ST;
        #pragma unroll
        for (int k = 0; k < KW; ++k)
            acc = fmaf(xr[k], wr[k], acc);
        if (n < nvalid)
            Ht[(size_t)o * NN + n0 + n] = fmaxf(acc, 0.f);
    }
}

__global__ __launch_bounds__(256) void k_fc(
    const float* __restrict__ Ht, const float* __restrict__ wcT,
    const float* __restrict__ bc, float* __restrict__ p1)
{
    int n = blockIdx.x * 256 + threadIdx.x;
    if (n >= NN) return;

    float acc[HID];
    #pragma unroll
    for (int l = 0; l < HID; ++l) acc[l] = bc[l];

    #pragma unroll 5
    for (int j = 0; j < FLAT; ++j) {
        float h = Ht[(size_t)j * NN + n];
        const float* w = wcT + j * HID;
        #pragma unroll
        for (int l = 0; l < HID; ++l)
            acc[l] = fmaf(h, w[l], acc[l]);
    }

    float4* po = (float4*)(p1 + (size_t)n * HID);
    po[0] = make_float4(acc[0],  acc[1],  acc[2],  acc[3]);
    po[1] = make_float4(acc[4],  acc[5],  acc[6],  acc[7]);
    po[2] = make_float4(acc[8],  acc[9],  acc[10], acc[11]);
    po[3] = make_float4(acc[12], acc[13], acc[14], acc[15]);
}

// ===========================================================================
// Dst-bucket edge sort (782 buckets of 128 dst nodes) -> esrt[] int2(src,dst)
// ===========================================================================
__global__ __launch_bounds__(256) void k_bhist(
    const int* __restrict__ ei, int* __restrict__ bcnt)
{
    __shared__ int h[NBKT];
    for (int i = threadIdx.x; i < NBKT; i += 256) h[i] = 0;
    __syncthreads();
    for (long long e = (long long)blockIdx.x * 256 + threadIdx.x; e < NE;
         e += (long long)gridDim.x * 256)
        atomicAdd(&h[ei[NE + e] >> BSH], 1);
    __syncthreads();
    for (int i = threadIdx.x; i < NBKT; i += 256)
        if (h[i]) atomicAdd(&bcnt[i], h[i]);
}

__global__ __launch_bounds__(256) void k_bscan(
    const int* __restrict__ bcnt, int* __restrict__ bbase, int* __restrict__ bcur)
{
    __shared__ int s[256];
    const int tid = threadIdx.x;
    const int chunk = (NBKT + 255) / 256;   // 4
    int lo = tid * chunk;
    int hi = min(lo + chunk, NBKT);
    int sum = 0;
    for (int i = lo; i < hi; ++i) sum += bcnt[i];
    s[tid] = sum;
    __syncthreads();
    if (tid == 0) {
        int run = 0;
        for (int i = 0; i < 256; ++i) { int v = s[i]; s[i] = run; run += v; }
        bbase[NBKT] = NE;
    }
    __syncthreads();
    int run = s[tid];
    for (int i = lo; i < hi; ++i) { bbase[i] = run; bcur[i] = run; run += bcnt[i]; }
}

// Block-grouped fill: per-block LDS histogram -> one range-reservation atomic
// per (block,bucket) -> contiguous int2 (src,dst) writes in dst-bucket order.
__global__ __launch_bounds__(256) void k_bfill(
    const int* __restrict__ ei, int* __restrict__ bcur,
    int2* __restrict__ esrt)
{
    __shared__ int h[NBKT];
    const long long e0 = (long long)blockIdx.x * FILL_CHUNK;
    const int cnt = (int)min((long long)FILL_CHUNK, (long long)NE - e0);

    for (int i = threadIdx.x; i < NBKT; i += 256) h[i] = 0;
    __syncthreads();
    for (int i = threadIdx.x; i < cnt; i += 256)
        atomicAdd(&h[ei[NE + e0 + i] >> BSH], 1);
    __syncthreads();
    for (int i = threadIdx.x; i < NBKT; i += 256) {
        int c = h[i];
        h[i] = c ? atomicAdd(&bcur[i], c) : 0;   // h[i] becomes write cursor
    }
    __syncthreads();
    for (int i = threadIdx.x; i < cnt; i += 256) {
        int src = ei[e0 + i];
        int dst = ei[NE + e0 + i];
        int slot = atomicAdd(&h[dst >> BSH], 1);
        esrt[slot] = make_int2(src, dst);
    }
}

// ===========================================================================
// Loop-free scatter over dst-sorted edges: thread = (edge, k).  Max request
// concurrency (round-2 structure); sorted order gives agg-line temporal
// locality so atomics stop bouncing lines across XCDs.
// ===========================================================================
__global__ __launch_bounds__(256) void k_scat(
    const float* __restrict__ p, const int2* __restrict__ esrt,
    float* __restrict__ agg)
{
    long long t = (long long)blockIdx.x * 256 + threadIdx.x;
    int e = (int)(t >> 4);
    if (e >= NE) return;
    int k = (int)(t & 15);
    int2 sd = esrt[e];                       // broadcast across the 16 lanes
    float v = p[(size_t)sd.x * HID + k];     // coalesced 64-B line per edge
    atomicAdd(agg + (size_t)sd.y * HID + k, v);
}

// ===========================================================================
// MLP epilogues (unchanged)
// ===========================================================================
__global__ __launch_bounds__(256) void k_mlp1(
    const float* __restrict__ p1, const float* __restrict__ agg,
    const float* __restrict__ b1, const float* __restrict__ w2,
    const float* __restrict__ b2, const float* __restrict__ w3,
    float* __restrict__ p2)
{
    __shared__ float s_w2[HID * HID], s_w3[HID * HID], s_b1[HID], s_b2[HID];
    int tid = threadIdx.x;
    s_w2[tid] = w2[tid];
    s_w3[tid] = w3[tid];
    if (tid < HID) { s_b1[tid] = b1[tid]; s_b2[tid] = b2[tid]; }
    __syncthreads();

    int n = blockIdx.x * 256 + tid;
    if (n >= NN) return;

    float t[HID], h[HID];
    const float4* pa = (const float4*)(p1  + (size_t)n * HID);
    const float4* pb = (const float4*)(agg + (size_t)n * HID);
    #pragma unroll
    for (int i = 0; i < 4; ++i) {
        float4 a = pa[i], b = pb[i];
        t[i*4+0] = fmaxf(a.x + b.x + s_b1[i*4+0], 0.f);
        t[i*4+1] = fmaxf(a.y + b.y + s_b1[i*4+1], 0.f);
        t[i*4+2] = fmaxf(a.z + b.z + s_b1[i*4+2], 0.f);
        t[i*4+3] = fmaxf(a.w + b.w + s_b1[i*4+3], 0.f);
    }
    #pragma unroll
    for (int i = 0; i < HID; ++i) {
        float acc = s_b2[i];
        #pragma unroll
        for (int j = 0; j < HID; ++j) acc += t[j] * s_w2[i * HID + j];
        h[i] = fmaxf(acc, 0.f);
    }
    float o[HID];
    #pragma unroll
    for (int i = 0; i < HID; ++i) {
        float acc = 0.f;
        #pragma unroll
        for (int j = 0; j < HID; ++j) acc += h[j] * s_w3[i * HID + j];
        o[i] = acc;
    }
    float4* po = (float4*)(p2 + (size_t)n * HID);
    #pragma unroll
    for (int i = 0; i < 4; ++i)
        po[i] = make_float4(o[i*4+0], o[i*4+1], o[i*4+2], o[i*4+3]);
}

__global__ __launch_bounds__(256) void k_final(
    const float* __restrict__ p2, const float* __restrict__ agg2,
    const float* __restrict__ b1, const float* __restrict__ w2,
    const float* __restrict__ b2, const float* __restrict__ row,
    const float* __restrict__ rob,
    float* __restrict__ out)
{
    __shared__ float s_w2[HID * HID], s_b1[HID], s_b2[HID], s_ro[HID];
    int tid = threadIdx.x;
    s_w2[tid] = w2[tid];
    if (tid < HID) { s_b1[tid] = b1[tid]; s_b2[tid] = b2[tid]; s_ro[tid] = row[tid]; }
    __syncthreads();

    int n = blockIdx.x * 256 + tid;
    if (n >= NN) return;

    float t[HID];
    const float4* pa = (const float4*)(p2   + (size_t)n * HID);
    const float4* pb = (const float4*)(agg2 + (size_t)n * HID);
    #pragma unroll
    for (int i = 0; i < 4; ++i) {
        float4 a = pa[i], b = pb[i];
        t[i*4+0] = fmaxf(a.x + b.x + s_b1[i*4+0], 0.f);
        t[i*4+1] = fmaxf(a.y + b.y + s_b1[i*4+1], 0.f);
        t[i*4+2] = fmaxf(a.z + b.z + s_b1[i*4+2], 0.f);
        t[i*4+3] = fmaxf(a.w + b.w + s_b1[i*4+3], 0.f);
    }
    float res = rob[0];
    #pragma unroll
    for (int i = 0; i < HID; ++i) {
        float acc = s_b2[i];
        #pragma unroll
        for (int j = 0; j < HID; ++j) acc += t[j] * s_w2[i * HID + j];
        res += acc * s_ro[i];
    }
    out[n] = res;
}

// ===========================================================================
// Fallback (round-1 structure) — only if workspace too small
// ===========================================================================
__global__ __launch_bounds__(256) void k_embed(
    const float* __restrict__ x,
    const float* __restrict__ conv_w, const float* __restrict__ conv_b,
    const float* __restrict__ fc_w,   const float* __restrict__ fc_b,
    const float* __restrict__ g1w1,
    float* __restrict__ p1)
{
    __shared__ float s_x[4][TL];
    __shared__ float s_h[4][FLAT + 3];
    __shared__ float s_e[4][EMB];

    const int w    = threadIdx.x >> 6;
    const int lane = threadIdx.x & 63;
    const int node = blockIdx.x * 4 + w;

    const float2* xr = (const float2*)(x + (size_t)node * TL);
    float2 v = xr[lane];
    s_x[w][lane * 2 + 0] = v.x;
    s_x[w][lane * 2 + 1] = v.y;
    __syncthreads();

    for (int o = lane; o < FLAT; o += 64) {
        int c = o / CL;
        int t = o - c * CL;
        float acc = conv_b[c];
        #pragma unroll
        for (int k = 0; k < KW; ++k)
            acc += s_x[w][t * ST + k] * conv_w[c * KW + k];
        s_h[w][o] = fmaxf(acc, 0.f);
    }
    __syncthreads();

    if (lane < EMB) {
        float acc = fc_b[lane];
        const float* wr = fc_w + lane * FLAT;
        for (int j = 0; j < FLAT; ++j)
            acc += s_h[w][j] * wr[j];
        s_e[w][lane] = acc;
    }
    __syncthreads();

    if (lane < HID) {
        float acc = 0.f;
        const float* wr = g1w1 + lane * EMB;
        #pragma unroll
        for (int j = 0; j < EMB; ++j)
            acc += s_e[w][j] * wr[j];
        p1[(size_t)node * HID + lane] = acc;
    }
}

__global__ __launch_bounds__(256) void k_scatter(
    const float* __restrict__ p, const int* __restrict__ ei,
    float* __restrict__ agg)
{
    long long t = (long long)blockIdx.x * 256 + threadIdx.x;
    int e = (int)(t >> 4);
    int k = (int)(t & 15);
    if (e >= NE) return;
    int src = ei[e];
    int dst = ei[NE + e];
    float v = p[(size_t)src * HID + k];
    atomicAdd(agg + (size_t)dst * HID + k, v);
}

// ===========================================================================
extern "C" void kernel_launch(void* const* d_in, const int* in_sizes, int n_in,
                              void* d_out, int out_size, void* d_ws, size_t ws_size,
                              hipStream_t stream)
{
    const float* x      = (const float*)d_in[0];
    const int*   ei     = (const int*)  d_in[1];
    const float* conv_w = (const float*)d_in[2];
    const float* conv_b = (const float*)d_in[3];
    const float* fc_w   = (const float*)d_in[4];
    const float* fc_b   = (const float*)d_in[5];
    const float* g1w1   = (const float*)d_in[6];
    const float* g1b1   = (const float*)d_in[7];
    const float* g1w2   = (const float*)d_in[8];
    const float* g1b2   = (const float*)d_in[9];
    const float* g2w1   = (const float*)d_in[10];
    const float* g2b1   = (const float*)d_in[11];
    const float* g2w2   = (const float*)d_in[12];
    const float* g2b2   = (const float*)d_in[13];
    const float* ro_w   = (const float*)d_in[14];
    const float* ro_b   = (const float*)d_in[15];
    float* out = (float*)d_out;

    // workspace: A[NN*16] B[NN*16] wcT[205*16] bc[16] Ht[205*NN]
    // Ht region reused after k_fc for: bcnt[NBKT] bbase[NBKT+1] bcur[NBKT]
    //                                  esrt[NE] int2 (~25.6 MB << 82 MB)
    float* A   = (float*)d_ws;
    float* B   = A + (size_t)NN * HID;
    float* wcT = B + (size_t)NN * HID;
    float* bc  = wcT + (size_t)FLAT * HID;
    float* Ht  = bc + 16;
    const size_t need = ((size_t)NN * HID * 2 + (size_t)FLAT * HID + 16 +
                         (size_t)FLAT * NN) * sizeof(float);

    int* bcnt  = (int*)Ht;
    int* bbase = bcnt + NBKT;
    int* bcur  = bbase + NBKT + 1;
    int2* esrt = (int2*)(bcur + NBKT + 1);   // 8-byte aligned

    const int SCAT_GRID = (int)(((long long)NE * HID + 255) / 256);

    if (ws_size >= need) {
        // embedding
        k_prep<<<1, 256, 0, stream>>>(g1w1, fc_w, fc_b, wcT, bc);
        k_conv<<<(NN + 63) / 64, 256, 0, stream>>>(x, conv_w, conv_b, Ht);
        k_fc<<<(NN + 255) / 256, 256, 0, stream>>>(Ht, wcT, bc, A);

        // dst-bucket sort of edges (Ht region dead now)
        hipMemsetAsync(bcnt, 0, NBKT * sizeof(int), stream);
        k_bhist<<<1024, 256, 0, stream>>>(ei, bcnt);
        k_bscan<<<1, 256, 0, stream>>>(bcnt, bbase, bcur);
        k_bfill<<<(NE + FILL_CHUNK - 1) / FILL_CHUNK, 256, 0, stream>>>(
            ei, bcur, esrt);

        // GIN layer 1: loop-free sorted scatter
        hipMemsetAsync(B, 0, (size_t)NN * HID * sizeof(float), stream);
        k_scat<<<SCAT_GRID, 256, 0, stream>>>(A, esrt, B);
        k_mlp1<<<(NN + 255) / 256, 256, 0, stream>>>(A, B, g1b1, g1w2, g1b2,
                                                     g2w1, A);
        // GIN layer 2
        hipMemsetAsync(B, 0, (size_t)NN * HID * sizeof(float), stream);
        k_scat<<<SCAT_GRID, 256, 0, stream>>>(A, esrt, B);
        k_final<<<(NN + 255) / 256, 256, 0, stream>>>(A, B, g2b1, g2w2, g2b2,
                                                      ro_w, ro_b, out);
    } else {
        // fallback: round-1 structure
        k_embed<<<NN / 4, 256, 0, stream>>>(x, conv_w, conv_b, fc_w, fc_b,
                                            g1w1, A);
        hipMemsetAsync(B, 0, (size_t)NN * HID * sizeof(float), stream);
        k_scatter<<<SCAT_GRID, 256, 0, stream>>>(A, ei, B);
        k_mlp1<<<(NN + 255) / 256, 256, 0, stream>>>(A, B, g1b1, g1w2, g1b2,
                                                     g2w1, A);
        hipMemsetAsync(B, 0, (size_t)NN * HID * sizeof(float), stream);
        k_scatter<<<SCAT_GRID, 256, 0, stream>>>(A, ei, B);
        k_final<<<(NN + 255) / 256, 256, 0, stream>>>(A, B, g2b1, g2w2, g2b2,
                                                      ro_w, ro_b, out);
    }
}